// Round 1
// baseline (306.734 us; speedup 1.0000x reference)
//
#include <hip/hip_runtime.h>

#define BN_EPS 1e-5f

constexpr int PN0 = 262144, PN1 = 65536, PN2 = 16384, PN3 = 4096;

// ---------------- histogram of gather indices ----------------
__global__ __launch_bounds__(256) void hist_kernel(const int* __restrict__ idx, int n,
                                                   int* __restrict__ cnt) {
    int i = blockIdx.x * blockDim.x + threadIdx.x;
    if (i < n) atomicAdd(&cnt[idx[i]], 1);
}

// ---------------- count-weighted per-channel sum / sumsq over source ----------------
// src: [R, C] row-major. Each thread owns one channel, loops rowsPerBlock rows.
__global__ __launch_bounds__(128) void stats_kernel(const float* __restrict__ src,
                                                    const int* __restrict__ cnt,
                                                    int C, int rowsPerBlock,
                                                    float* __restrict__ sum,
                                                    float* __restrict__ sumsq) {
    int c = blockIdx.x * blockDim.x + threadIdx.x;
    int r0 = blockIdx.y * rowsPerBlock;
    float s = 0.f, q = 0.f;
    for (int r = r0; r < r0 + rowsPerBlock; ++r) {
        float w = (float)cnt[r];
        float v = src[(size_t)r * C + c];
        s += w * v;
        q += w * v * v;
    }
    atomicAdd(&sum[c], s);
    atomicAdd(&sumsq[c], q);
}

// ---------------- fold BN into per-channel scale/shift ----------------
__global__ __launch_bounds__(128) void finalize_kernel(const float* __restrict__ sum,
                                                       const float* __restrict__ sumsq,
                                                       const float* __restrict__ bnw,
                                                       const float* __restrict__ bnb,
                                                       float invN, int C,
                                                       float* __restrict__ scale,
                                                       float* __restrict__ shift) {
    int c = blockIdx.x * blockDim.x + threadIdx.x;
    if (c >= C) return;
    float mean = sum[c] * invN;
    float var  = fmaxf(sumsq[c] * invN - mean * mean, 0.f);
    float s = bnw[c] * rsqrtf(var + BN_EPS);
    scale[c] = s;
    shift[c] = bnb[c] - mean * s;
}

// ---------------- fused gather + BN-affine + GEMM + residual ----------------
// out[i][o] = base[i][o] + sum_c (src[idx[i]][c]*scale[c] + shift[c]) * W[o][c]
// Tile: BM=64, BN=64, BK=32. 256 threads, each computes 4x4 outputs.
// LDS tiles stored transposed: As[k][m], Bs[k][n] -> ds_read_b128 operand fetch.
__global__ __launch_bounds__(256) void gemm_kernel(const float* __restrict__ src,
                                                   const int* __restrict__ idx,
                                                   const float* __restrict__ W,
                                                   const float* __restrict__ scale,
                                                   const float* __restrict__ shift,
                                                   const float* __restrict__ base,
                                                   float* __restrict__ out,
                                                   int K, int N) {
    __shared__ float As[32][68];  // +4 pad keeps 16B alignment, breaks write conflicts
    __shared__ float Bs[32][68];

    const int tid = threadIdx.x;
    const int m0 = blockIdx.x * 64;
    const int n0 = blockIdx.y * 64;
    const int tx = tid & 15;   // 16 col-groups
    const int ty = tid >> 4;   // 16 row-groups

    float acc[4][4] = {};

    for (int k0 = 0; k0 < K; k0 += 32) {
        // stage: 64 rows x 32 k = 512 float4; 256 threads -> 2 each
        #pragma unroll
        for (int f = tid; f < 512; f += 256) {
            int row = f >> 3;       // 0..63
            int c4  = f & 7;        // 0..7, float4 along K
            int kk  = k0 + c4 * 4;
            int grow = idx[m0 + row];
            float4 v  = *reinterpret_cast<const float4*>(&src[(size_t)grow * K + kk]);
            float4 sc = *reinterpret_cast<const float4*>(&scale[kk]);
            float4 sh = *reinterpret_cast<const float4*>(&shift[kk]);
            As[c4 * 4 + 0][row] = v.x * sc.x + sh.x;
            As[c4 * 4 + 1][row] = v.y * sc.y + sh.y;
            As[c4 * 4 + 2][row] = v.z * sc.z + sh.z;
            As[c4 * 4 + 3][row] = v.w * sc.w + sh.w;
            float4 wv = *reinterpret_cast<const float4*>(&W[(size_t)(n0 + row) * K + kk]);
            Bs[c4 * 4 + 0][row] = wv.x;
            Bs[c4 * 4 + 1][row] = wv.y;
            Bs[c4 * 4 + 2][row] = wv.z;
            Bs[c4 * 4 + 3][row] = wv.w;
        }
        __syncthreads();

        #pragma unroll
        for (int k = 0; k < 32; ++k) {
            float4 av = *reinterpret_cast<const float4*>(&As[k][ty * 4]);
            float4 bv = *reinterpret_cast<const float4*>(&Bs[k][tx * 4]);
            float a[4] = {av.x, av.y, av.z, av.w};
            float b[4] = {bv.x, bv.y, bv.z, bv.w};
            #pragma unroll
            for (int m = 0; m < 4; ++m)
                #pragma unroll
                for (int n = 0; n < 4; ++n)
                    acc[m][n] += a[m] * b[n];
        }
        __syncthreads();
    }

    // epilogue: residual add, float4 stores
    #pragma unroll
    for (int m = 0; m < 4; ++m) {
        size_t row = (size_t)(m0 + ty * 4 + m);
        size_t off = row * N + n0 + tx * 4;
        float4 bv = *reinterpret_cast<const float4*>(&base[off]);
        float4 o;
        o.x = bv.x + acc[m][0];
        o.y = bv.y + acc[m][1];
        o.z = bv.z + acc[m][2];
        o.w = bv.w + acc[m][3];
        *reinterpret_cast<float4*>(&out[off]) = o;
    }
}

extern "C" void kernel_launch(void* const* d_in, const int* in_sizes, int n_in,
                              void* d_out, int out_size, void* d_ws, size_t ws_size,
                              hipStream_t stream) {
    const float* f0    = (const float*)d_in[0];
    const float* f1    = (const float*)d_in[1];
    const float* f2    = (const float*)d_in[2];
    const float* f3    = (const float*)d_in[3];
    const float* bn_w2 = (const float*)d_in[4];
    const float* bn_b2 = (const float*)d_in[5];
    const float* W2    = (const float*)d_in[6];
    const float* bn_w1 = (const float*)d_in[7];
    const float* bn_b1 = (const float*)d_in[8];
    const float* W1    = (const float*)d_in[9];
    const float* bn_w0 = (const float*)d_in[10];
    const float* bn_b0 = (const float*)d_in[11];
    const float* W0    = (const float*)d_in[12];
    const int*   idx0  = (const int*)d_in[13];
    const int*   idx1  = (const int*)d_in[14];
    const int*   idx2  = (const int*)d_in[15];
    float* out = (float*)d_out;

    // ---- workspace layout ----
    float* f2p = (float*)d_ws;                       // [PN2, 256]
    float* f1p = f2p + (size_t)PN2 * 256;            // [PN1, 128]
    int*   cnt3 = (int*)(f1p + (size_t)PN1 * 128);   // [PN3]  -- zero region start
    int*   cnt2 = cnt3 + PN3;                        // [PN2]
    int*   cnt1 = cnt2 + PN2;                        // [PN1]
    float* sum2 = (float*)(cnt1 + PN1);              // 512
    float* sq2  = sum2 + 512;
    float* sum1 = sq2 + 512;                         // 256
    float* sq1  = sum1 + 256;
    float* sum0 = sq1 + 256;                         // 128
    float* sq0  = sum0 + 128;                        // zero region end
    float* scale2 = sq0 + 128;
    float* shift2 = scale2 + 512;
    float* scale1 = shift2 + 512;
    float* shift1 = scale1 + 256;
    float* scale0 = shift1 + 256;
    float* shift0 = scale0 + 128;

    size_t zeroBytes = (size_t)((char*)(sq0 + 128) - (char*)cnt3);
    hipMemsetAsync(cnt3, 0, zeroBytes, stream);

    // histograms of gather indices
    hist_kernel<<<PN2 / 256, 256, 0, stream>>>(idx0, PN2, cnt3);
    hist_kernel<<<PN1 / 256, 256, 0, stream>>>(idx1, PN1, cnt2);
    hist_kernel<<<PN0 / 256, 256, 0, stream>>>(idx2, PN0, cnt1);

    // ---- level 2: f2' = f2 + BN(f3[idx0]) @ W2^T ----
    stats_kernel<<<dim3(512 / 128, PN3 / 32), 128, 0, stream>>>(f3, cnt3, 512, 32, sum2, sq2);
    finalize_kernel<<<4, 128, 0, stream>>>(sum2, sq2, bn_w2, bn_b2, 1.f / PN2, 512, scale2, shift2);
    gemm_kernel<<<dim3(PN2 / 64, 256 / 64), 256, 0, stream>>>(f3, idx0, W2, scale2, shift2,
                                                              f2, f2p, 512, 256);

    // ---- level 1: f1' = f1 + BN(f2'[idx1]) @ W1^T ----
    stats_kernel<<<dim3(256 / 128, PN2 / 32), 128, 0, stream>>>(f2p, cnt2, 256, 32, sum1, sq1);
    finalize_kernel<<<2, 128, 0, stream>>>(sum1, sq1, bn_w1, bn_b1, 1.f / PN1, 256, scale1, shift1);
    gemm_kernel<<<dim3(PN1 / 64, 128 / 64), 256, 0, stream>>>(f2p, idx1, W1, scale1, shift1,
                                                              f1, f1p, 256, 128);

    // ---- level 0: out = f0 + BN(f1'[idx2]) @ W0^T ----
    stats_kernel<<<dim3(1, PN1 / 64), 128, 0, stream>>>(f1p, cnt1, 128, 64, sum0, sq0);
    finalize_kernel<<<1, 128, 0, stream>>>(sum0, sq0, bn_w0, bn_b0, 1.f / PN0, 128, scale0, shift0);
    gemm_kernel<<<dim3(PN0 / 64, 64 / 64), 256, 0, stream>>>(f1p, idx2, W0, scale0, shift0,
                                                             f0, out, 128, 64);
}

// Round 2
// 194.169 us; speedup vs baseline: 1.5797x; 1.5797x over previous
//
#include <hip/hip_runtime.h>

#define BN_EPS 1e-5f

constexpr int PN0 = 262144, PN1 = 65536, PN2 = 16384, PN3 = 4096;

typedef __attribute__((ext_vector_type(8))) short short8;
typedef __attribute__((ext_vector_type(4))) float f32x4;

__device__ __forceinline__ unsigned int f2bf(float f) {
    unsigned u = __builtin_bit_cast(unsigned, f);
    u += 0x7fff + ((u >> 16) & 1);
    return u >> 16;
}

// ---------------- histogram of gather indices ----------------
__global__ __launch_bounds__(256) void hist_kernel(const int* __restrict__ idx, int n,
                                                   int* __restrict__ cnt) {
    int i = blockIdx.x * blockDim.x + threadIdx.x;
    if (i < n) atomicAdd(&cnt[idx[i]], 1);
}

// ---------------- count-weighted per-channel sum / sumsq over source ----------------
__global__ __launch_bounds__(128) void stats_kernel(const float* __restrict__ src,
                                                    const int* __restrict__ cnt,
                                                    int C, int rowsPerBlock,
                                                    float* __restrict__ sum,
                                                    float* __restrict__ sumsq) {
    int c = blockIdx.x * blockDim.x + threadIdx.x;
    int r0 = blockIdx.y * rowsPerBlock;
    float s = 0.f, q = 0.f;
    for (int r = r0; r < r0 + rowsPerBlock; ++r) {
        float w = (float)cnt[r];
        float v = src[(size_t)r * C + c];
        s += w * v;
        q += w * v * v;
    }
    atomicAdd(&sum[c], s);
    atomicAdd(&sumsq[c], q);
}

// ---------------- fold BN into per-channel scale/shift ----------------
__global__ __launch_bounds__(128) void finalize_kernel(const float* __restrict__ sum,
                                                       const float* __restrict__ sumsq,
                                                       const float* __restrict__ bnw,
                                                       const float* __restrict__ bnb,
                                                       float invN, int C,
                                                       float* __restrict__ scale,
                                                       float* __restrict__ shift) {
    int c = blockIdx.x * blockDim.x + threadIdx.x;
    if (c >= C) return;
    float mean = sum[c] * invN;
    float var  = fmaxf(sumsq[c] * invN - mean * mean, 0.f);
    float s = bnw[c] * rsqrtf(var + BN_EPS);
    scale[c] = s;
    shift[c] = bnb[c] - mean * s;
}

// ---------------- fused gather + BN-affine + bf16 MFMA GEMM + residual ----------------
// out[i][o] = base[i][o] + sum_c (src[idx[i]][c]*scale[c] + shift[c]) * W[o][c]
// BM=128, BN=64, BK=64. 256 threads = 4 waves in 2x2; wave computes 64x32 (4x2 frags).
// LDS row-major bf16 tiles, 128B/row, XOR-swizzled ((row&7)<<4 on byte offs) so
// ds_read_b128 operand fetch is conflict-free (2-way, which is free).
template<int KTILES, int N>
__global__ __launch_bounds__(256) void gemm_mfma(const float* __restrict__ src,
                                                 const int* __restrict__ idx,
                                                 const float* __restrict__ W,
                                                 const float* __restrict__ scale,
                                                 const float* __restrict__ shift,
                                                 const float* __restrict__ base,
                                                 float* __restrict__ out) {
    constexpr int K = KTILES * 64;
    __shared__ unsigned short As[128 * 64];  // 16 KB
    __shared__ unsigned short Bs[64 * 64];   //  8 KB

    const int tid  = threadIdx.x;
    const int lane = tid & 63;
    const int wave = tid >> 6;
    const int wm = wave >> 1, wn = wave & 1;
    const int l15 = lane & 15, lg = lane >> 4;
    const int m0 = blockIdx.x * 128;
    const int n0 = blockIdx.y * 64;

    // staging coords: thread handles rows (tid>>4)+16*it at k-chunk (tid&15)*4
    const int srow = tid >> 4;
    const int skc  = tid & 15;

    const float* aptr[8];
    #pragma unroll
    for (int it = 0; it < 8; ++it)
        aptr[it] = src + (size_t)idx[m0 + srow + 16 * it] * K + skc * 4;
    const float* bptr[4];
    #pragma unroll
    for (int it = 0; it < 4; ++it)
        bptr[it] = W + (size_t)(n0 + srow + 16 * it) * K + skc * 4;

    float4 areg[8];
    float4 breg[4];
    float4 screg, shreg;

    f32x4 acc[4][2];
    #pragma unroll
    for (int mi = 0; mi < 4; ++mi)
        #pragma unroll
        for (int ni = 0; ni < 2; ++ni)
            acc[mi][ni] = (f32x4){0.f, 0.f, 0.f, 0.f};

    auto LOADT = [&](int kt) {
        const int k0 = kt * 64;
        #pragma unroll
        for (int it = 0; it < 8; ++it)
            areg[it] = *reinterpret_cast<const float4*>(aptr[it] + k0);
        #pragma unroll
        for (int it = 0; it < 4; ++it)
            breg[it] = *reinterpret_cast<const float4*>(bptr[it] + k0);
        screg = *reinterpret_cast<const float4*>(&scale[k0 + skc * 4]);
        shreg = *reinterpret_cast<const float4*>(&shift[k0 + skc * 4]);
    };

    auto WRITET = [&]() {
        #pragma unroll
        for (int it = 0; it < 8; ++it) {
            const int row = srow + 16 * it;
            float x = areg[it].x * screg.x + shreg.x;
            float y = areg[it].y * screg.y + shreg.y;
            float z = areg[it].z * screg.z + shreg.z;
            float w = areg[it].w * screg.w + shreg.w;
            unsigned lo = f2bf(x) | (f2bf(y) << 16);
            unsigned hi = f2bf(z) | (f2bf(w) << 16);
            const int ai = (row * 64 + skc * 4) ^ ((row & 7) << 3);  // ushort units
            *reinterpret_cast<uint2*>(&As[ai]) = make_uint2(lo, hi);
        }
        #pragma unroll
        for (int it = 0; it < 4; ++it) {
            const int col = srow + 16 * it;
            unsigned lo = f2bf(breg[it].x) | (f2bf(breg[it].y) << 16);
            unsigned hi = f2bf(breg[it].z) | (f2bf(breg[it].w) << 16);
            const int bi = (col * 64 + skc * 4) ^ ((col & 7) << 3);
            *reinterpret_cast<uint2*>(&Bs[bi]) = make_uint2(lo, hi);
        }
    };

    auto COMPUTE = [&]() {
        #pragma unroll
        for (int kk = 0; kk < 2; ++kk) {
            short8 bfr[2];
            #pragma unroll
            for (int ni = 0; ni < 2; ++ni) {
                const int col = wn * 32 + ni * 16 + l15;
                const int bi = (col * 64 + kk * 32 + lg * 8) ^ ((col & 7) << 3);
                bfr[ni] = *reinterpret_cast<const short8*>(&Bs[bi]);
            }
            #pragma unroll
            for (int mi = 0; mi < 4; ++mi) {
                const int row = wm * 64 + mi * 16 + l15;
                const int ai = (row * 64 + kk * 32 + lg * 8) ^ ((row & 7) << 3);
                short8 afr = *reinterpret_cast<const short8*>(&As[ai]);
                #pragma unroll
                for (int ni = 0; ni < 2; ++ni)
                    acc[mi][ni] = __builtin_amdgcn_mfma_f32_16x16x32_bf16(
                        afr, bfr[ni], acc[mi][ni], 0, 0, 0);
            }
        }
    };

    LOADT(0);
    for (int kt = 0; kt < KTILES; ++kt) {
        WRITET();
        __syncthreads();
        if (kt + 1 < KTILES) LOADT(kt + 1);
        COMPUTE();
        __syncthreads();
    }

    // epilogue: residual add; C/D layout col=lane&15, row=(lane>>4)*4+reg
    #pragma unroll
    for (int mi = 0; mi < 4; ++mi) {
        #pragma unroll
        for (int ni = 0; ni < 2; ++ni) {
            const int col  = n0 + wn * 32 + ni * 16 + l15;
            const int rowb = m0 + wm * 64 + mi * 16 + lg * 4;
            #pragma unroll
            for (int r = 0; r < 4; ++r) {
                size_t off = (size_t)(rowb + r) * N + col;
                out[off] = base[off] + acc[mi][ni][r];
            }
        }
    }
}

extern "C" void kernel_launch(void* const* d_in, const int* in_sizes, int n_in,
                              void* d_out, int out_size, void* d_ws, size_t ws_size,
                              hipStream_t stream) {
    const float* f0    = (const float*)d_in[0];
    const float* f1    = (const float*)d_in[1];
    const float* f2    = (const float*)d_in[2];
    const float* f3    = (const float*)d_in[3];
    const float* bn_w2 = (const float*)d_in[4];
    const float* bn_b2 = (const float*)d_in[5];
    const float* W2    = (const float*)d_in[6];
    const float* bn_w1 = (const float*)d_in[7];
    const float* bn_b1 = (const float*)d_in[8];
    const float* W1    = (const float*)d_in[9];
    const float* bn_w0 = (const float*)d_in[10];
    const float* bn_b0 = (const float*)d_in[11];
    const float* W0    = (const float*)d_in[12];
    const int*   idx0  = (const int*)d_in[13];
    const int*   idx1  = (const int*)d_in[14];
    const int*   idx2  = (const int*)d_in[15];
    float* out = (float*)d_out;

    // ---- workspace layout ----
    float* f2p = (float*)d_ws;                       // [PN2, 256]
    float* f1p = f2p + (size_t)PN2 * 256;            // [PN1, 128]
    int*   cnt3 = (int*)(f1p + (size_t)PN1 * 128);   // [PN3]  -- zero region start
    int*   cnt2 = cnt3 + PN3;                        // [PN2]
    int*   cnt1 = cnt2 + PN2;                        // [PN1]
    float* sum2 = (float*)(cnt1 + PN1);              // 512
    float* sq2  = sum2 + 512;
    float* sum1 = sq2 + 512;                         // 256
    float* sq1  = sum1 + 256;
    float* sum0 = sq1 + 256;                         // 128
    float* sq0  = sum0 + 128;                        // zero region end
    float* scale2 = sq0 + 128;
    float* shift2 = scale2 + 512;
    float* scale1 = shift2 + 512;
    float* shift1 = scale1 + 256;
    float* scale0 = shift1 + 256;
    float* shift0 = scale0 + 128;

    size_t zeroBytes = (size_t)((char*)(sq0 + 128) - (char*)cnt3);
    hipMemsetAsync(cnt3, 0, zeroBytes, stream);

    // histograms of gather indices
    hist_kernel<<<PN2 / 256, 256, 0, stream>>>(idx0, PN2, cnt3);
    hist_kernel<<<PN1 / 256, 256, 0, stream>>>(idx1, PN1, cnt2);
    hist_kernel<<<PN0 / 256, 256, 0, stream>>>(idx2, PN0, cnt1);

    // ---- level 2: f2' = f2 + BN(f3[idx0]) @ W2^T ----
    stats_kernel<<<dim3(512 / 128, PN3 / 32), 128, 0, stream>>>(f3, cnt3, 512, 32, sum2, sq2);
    finalize_kernel<<<4, 128, 0, stream>>>(sum2, sq2, bn_w2, bn_b2, 1.f / PN2, 512, scale2, shift2);
    gemm_mfma<8, 256><<<dim3(PN2 / 128, 4), 256, 0, stream>>>(f3, idx0, W2, scale2, shift2, f2, f2p);

    // ---- level 1: f1' = f1 + BN(f2'[idx1]) @ W1^T ----
    stats_kernel<<<dim3(256 / 128, PN2 / 32), 128, 0, stream>>>(f2p, cnt2, 256, 32, sum1, sq1);
    finalize_kernel<<<2, 128, 0, stream>>>(sum1, sq1, bn_w1, bn_b1, 1.f / PN1, 256, scale1, shift1);
    gemm_mfma<4, 128><<<dim3(PN1 / 128, 2), 256, 0, stream>>>(f2p, idx1, W1, scale1, shift1, f1, f1p);

    // ---- level 0: out = f0 + BN(f1'[idx2]) @ W0^T ----
    stats_kernel<<<dim3(1, PN1 / 64), 128, 0, stream>>>(f1p, cnt1, 128, 64, sum0, sq0);
    finalize_kernel<<<1, 128, 0, stream>>>(sum0, sq0, bn_w0, bn_b0, 1.f / PN0, 128, scale0, shift0);
    gemm_mfma<2, 64><<<dim3(PN0 / 128, 1), 256, 0, stream>>>(f1p, idx2, W0, scale0, shift0, f0, out);
}

// Round 3
// 191.494 us; speedup vs baseline: 1.6018x; 1.0140x over previous
//
#include <hip/hip_runtime.h>

#define BN_EPS 1e-5f

constexpr int PN0 = 262144, PN1 = 65536, PN2 = 16384, PN3 = 4096;

typedef __attribute__((ext_vector_type(8))) short short8;
typedef __attribute__((ext_vector_type(4))) float f32x4;

__device__ __forceinline__ unsigned f2bf(float f) {
    unsigned u = __builtin_bit_cast(unsigned, f);
    u += 0x7fff + ((u >> 16) & 1);
    return u >> 16;
}
__device__ __forceinline__ float bf2f(unsigned h) {
    return __builtin_bit_cast(float, h << 16);
}

// ---------------- fused histogram of all three gather-index arrays ----------------
__global__ __launch_bounds__(256) void hist_all(const int* __restrict__ idx0,
                                                const int* __restrict__ idx1,
                                                const int* __restrict__ idx2,
                                                int* __restrict__ cnt3,
                                                int* __restrict__ cnt2,
                                                int* __restrict__ cnt1) {
    int i = blockIdx.x * 256 + threadIdx.x;
    if (blockIdx.y == 0) {
        if (i < PN2) atomicAdd(&cnt3[idx0[i]], 1);
    } else if (blockIdx.y == 1) {
        if (i < PN1) atomicAdd(&cnt2[idx1[i]], 1);
    } else {
        atomicAdd(&cnt1[idx2[i]], 1);
    }
}

// ---------------- weighted stats over f3 (f32, C=512) -> per-block partials ----------------
// part layout: [gridDim.x][512][2]
__global__ __launch_bounds__(256) void stats_f3(const float* __restrict__ f3,
                                                const int* __restrict__ cnt,
                                                float* __restrict__ part) {
    __shared__ float red[4][64][8];
    const int tid = threadIdx.x;
    const int cg = tid & 63;   // channel group: channels cg*8..+8
    const int lr = tid >> 6;   // 4 row-lanes
    const int r0 = blockIdx.x * 16;
    float s[8] = {}, q[8] = {};
    #pragma unroll
    for (int i = 0; i < 4; ++i) {
        int r = r0 + lr + 4 * i;
        float w = (float)cnt[r];
        const float* p = f3 + (size_t)r * 512 + cg * 8;
        float4 a = *reinterpret_cast<const float4*>(p);
        float4 b = *reinterpret_cast<const float4*>(p + 4);
        float v[8] = {a.x, a.y, a.z, a.w, b.x, b.y, b.z, b.w};
        #pragma unroll
        for (int j = 0; j < 8; ++j) { s[j] += w * v[j]; q[j] += w * v[j] * v[j]; }
    }
    #pragma unroll
    for (int j = 0; j < 8; ++j) red[lr][cg][j] = s[j];
    __syncthreads();
    float ss[8];
    if (tid < 64) {
        #pragma unroll
        for (int j = 0; j < 8; ++j)
            ss[j] = red[0][tid][j] + red[1][tid][j] + red[2][tid][j] + red[3][tid][j];
    }
    __syncthreads();
    #pragma unroll
    for (int j = 0; j < 8; ++j) red[lr][cg][j] = q[j];
    __syncthreads();
    if (tid < 64) {
        #pragma unroll
        for (int j = 0; j < 8; ++j) {
            float qq = red[0][tid][j] + red[1][tid][j] + red[2][tid][j] + red[3][tid][j];
            size_t o = ((size_t)blockIdx.x * 512 + tid * 8 + j) * 2;
            part[o] = ss[j];
            part[o + 1] = qq;
        }
    }
}

// ---------------- reduce partials -> scale/shift ----------------
__global__ __launch_bounds__(256) void redfin(const float* __restrict__ part, int NB, int C,
                                              const float* __restrict__ bnw,
                                              const float* __restrict__ bnb,
                                              float invN,
                                              float* __restrict__ scale,
                                              float* __restrict__ shift) {
    const int tid = threadIdx.x;
    const int c = blockIdx.x * 32 + (tid >> 3);
    const int j = tid & 7;
    float s = 0.f, q = 0.f;
    for (int b = j; b < NB; b += 8) {
        const float* p = part + ((size_t)b * C + c) * 2;
        s += p[0];
        q += p[1];
    }
    s += __shfl_xor(s, 1); s += __shfl_xor(s, 2); s += __shfl_xor(s, 4);
    q += __shfl_xor(q, 1); q += __shfl_xor(q, 2); q += __shfl_xor(q, 4);
    if (j == 0) {
        float mean = s * invN;
        float var = fmaxf(q * invN - mean * mean, 0.f);
        float sc = bnw[c] * rsqrtf(var + BN_EPS);
        scale[c] = sc;
        shift[c] = bnb[c] - mean * sc;
    }
}

// ---------------- streaming gather-GEMM ----------------
// out[m][n] = base[m][n] + sum_k x[idx[m]][k]*W'[n][k] + d[n],
// W'[n][k] = scale[k]*W[n][k] (bf16, LDS-resident), d[n] = sum_k shift[k]*W[n][k].
// Block: 4 waves, grid-stride over 16-row chunks. mfma(W'frag, xfrag) -> lane holds
// row m = l15, 4 consecutive cols (lg*4+r). Optional fused weighted col-stats.
template<int K, bool SRC_BF16, bool OUT_F32, bool DO_STATS, bool HOIST>
__global__ __launch_bounds__(256, 3) void gemm_stream(const void* __restrict__ src,
                                                      const int* __restrict__ idx,
                                                      const float* __restrict__ W,
                                                      const float* __restrict__ scale,
                                                      const float* __restrict__ shift,
                                                      const float* __restrict__ base,
                                                      void* __restrict__ outv,
                                                      const int* __restrict__ cnt_next,
                                                      float* __restrict__ part,
                                                      int nchunks, int C) {
    constexpr int KK = K / 32;
    __shared__ unsigned short Wl[64 * K];
    __shared__ float dl[64];
    __shared__ float red[4][64][2];

    const int tid = threadIdx.x;
    const int lane = tid & 63;
    const int wv = tid >> 6;
    const int l15 = lane & 15, lg = lane >> 4;
    const int ncol0 = blockIdx.y * 64;

    // ---- stage W' (bf16, XOR-swizzled) + compute d ----
    {
        const int n = tid >> 2, kt = tid & 3;
        const float* wrow = W + (size_t)(ncol0 + n) * K;
        float dpart = 0.f;
        #pragma unroll
        for (int i = 0; i < K / 32; ++i) {
            int k = (kt + 4 * i) * 8;
            float4 w0 = *reinterpret_cast<const float4*>(wrow + k);
            float4 w1 = *reinterpret_cast<const float4*>(wrow + k + 4);
            float4 s0 = *reinterpret_cast<const float4*>(scale + k);
            float4 s1 = *reinterpret_cast<const float4*>(scale + k + 4);
            float4 h0 = *reinterpret_cast<const float4*>(shift + k);
            float4 h1 = *reinterpret_cast<const float4*>(shift + k + 4);
            dpart += h0.x * w0.x + h0.y * w0.y + h0.z * w0.z + h0.w * w0.w
                   + h1.x * w1.x + h1.y * w1.y + h1.z * w1.z + h1.w * w1.w;
            unsigned u0 = f2bf(w0.x * s0.x) | (f2bf(w0.y * s0.y) << 16);
            unsigned u1 = f2bf(w0.z * s0.z) | (f2bf(w0.w * s0.w) << 16);
            unsigned u2 = f2bf(w1.x * s1.x) | (f2bf(w1.y * s1.y) << 16);
            unsigned u3 = f2bf(w1.z * s1.z) | (f2bf(w1.w * s1.w) << 16);
            int si = (n * K + k) ^ ((n & 7) << 3);
            *reinterpret_cast<uint4*>(&Wl[si]) = make_uint4(u0, u1, u2, u3);
        }
        dpart += __shfl_xor(dpart, 1);
        dpart += __shfl_xor(dpart, 2);
        if (kt == 0) dl[n] = dpart;
    }
    __syncthreads();

    // d into regs (broadcast reads)
    float dr[4][4];
    #pragma unroll
    for (int ni = 0; ni < 4; ++ni) {
        float4 t = *reinterpret_cast<const float4*>(&dl[ni * 16 + lg * 4]);
        dr[ni][0] = t.x; dr[ni][1] = t.y; dr[ni][2] = t.z; dr[ni][3] = t.w;
    }

    auto rdW = [&](int kk, int ni) -> short8 {
        int si = ((ni * 16 + l15) * K + kk * 32 + lg * 8) ^ ((l15 & 7) << 3);
        return *reinterpret_cast<const short8*>(&Wl[si]);
    };

    short8 wf[HOIST ? KK : 1][4];
    if constexpr (HOIST) {
        #pragma unroll
        for (int kk = 0; kk < KK; ++kk)
            #pragma unroll
            for (int ni = 0; ni < 4; ++ni) wf[kk][ni] = rdW(kk, ni);
    }

    const unsigned short* srcb = (const unsigned short*)src;
    const float* srcf = (const float*)src;
    unsigned short* outb = (unsigned short*)outv;
    float* outf = (float*)outv;

    float s[4][4] = {}, q[4][4] = {};

    const int gw = blockIdx.x * 4 + wv;
    const int step = gridDim.x * 4;

    int g = 0; float w = 0.f;
    if (gw < nchunks) {
        g = idx[gw * 16 + l15];
        if constexpr (DO_STATS) w = (float)cnt_next[gw * 16 + l15];
    }

    for (int c = gw; c < nchunks; c += step) {
        // prefetch next chunk's index/weight
        int cn = c + step;
        int gn = 0; float wn = 0.f;
        if (cn < nchunks) {
            gn = idx[cn * 16 + l15];
            if constexpr (DO_STATS) wn = (float)cnt_next[cn * 16 + l15];
        }

        f32x4 acc[4];
        #pragma unroll
        for (int ni = 0; ni < 4; ++ni) acc[ni] = (f32x4){0.f, 0.f, 0.f, 0.f};

        #pragma unroll
        for (int kk = 0; kk < KK; ++kk) {
            short8 xf;
            if constexpr (SRC_BF16) {
                xf = *reinterpret_cast<const short8*>(srcb + (size_t)g * K + kk * 32 + lg * 8);
            } else {
                const float* p = srcf + (size_t)g * K + kk * 32 + lg * 8;
                float4 a = *reinterpret_cast<const float4*>(p);
                float4 b = *reinterpret_cast<const float4*>(p + 4);
                xf[0] = (short)f2bf(a.x); xf[1] = (short)f2bf(a.y);
                xf[2] = (short)f2bf(a.z); xf[3] = (short)f2bf(a.w);
                xf[4] = (short)f2bf(b.x); xf[5] = (short)f2bf(b.y);
                xf[6] = (short)f2bf(b.z); xf[7] = (short)f2bf(b.w);
            }
            #pragma unroll
            for (int ni = 0; ni < 4; ++ni) {
                short8 a = HOIST ? wf[HOIST ? kk : 0][ni] : rdW(kk, ni);
                acc[ni] = __builtin_amdgcn_mfma_f32_16x16x32_bf16(a, xf, acc[ni], 0, 0, 0);
            }
        }

        const int rowm = c * 16 + l15;
        #pragma unroll
        for (int ni = 0; ni < 4; ++ni) {
            size_t off = (size_t)rowm * C + ncol0 + ni * 16 + lg * 4;
            float4 bs = *reinterpret_cast<const float4*>(&base[off]);
            float v0 = bs.x + dr[ni][0] + acc[ni][0];
            float v1 = bs.y + dr[ni][1] + acc[ni][1];
            float v2 = bs.z + dr[ni][2] + acc[ni][2];
            float v3 = bs.w + dr[ni][3] + acc[ni][3];
            if constexpr (OUT_F32) {
                *reinterpret_cast<float4*>(&outf[off]) = make_float4(v0, v1, v2, v3);
            } else {
                unsigned h0 = f2bf(v0), h1 = f2bf(v1), h2 = f2bf(v2), h3 = f2bf(v3);
                *reinterpret_cast<uint2*>(&outb[off]) = make_uint2(h0 | (h1 << 16), h2 | (h3 << 16));
                if constexpr (DO_STATS) {
                    float r0 = bf2f(h0), r1 = bf2f(h1), r2 = bf2f(h2), r3 = bf2f(h3);
                    s[ni][0] += w * r0; q[ni][0] += w * r0 * r0;
                    s[ni][1] += w * r1; q[ni][1] += w * r1 * r1;
                    s[ni][2] += w * r2; q[ni][2] += w * r2 * r2;
                    s[ni][3] += w * r3; q[ni][3] += w * r3 * r3;
                }
            }
        }
        g = gn; w = wn;
    }

    if constexpr (DO_STATS) {
        #pragma unroll
        for (int ni = 0; ni < 4; ++ni)
            #pragma unroll
            for (int r = 0; r < 4; ++r) {
                float sv = s[ni][r], qv = q[ni][r];
                sv += __shfl_xor(sv, 1); qv += __shfl_xor(qv, 1);
                sv += __shfl_xor(sv, 2); qv += __shfl_xor(qv, 2);
                sv += __shfl_xor(sv, 4); qv += __shfl_xor(qv, 4);
                sv += __shfl_xor(sv, 8); qv += __shfl_xor(qv, 8);
                s[ni][r] = sv; q[ni][r] = qv;
            }
        if (l15 == 0) {
            #pragma unroll
            for (int ni = 0; ni < 4; ++ni)
                #pragma unroll
                for (int r = 0; r < 4; ++r) {
                    int col = ni * 16 + lg * 4 + r;
                    red[wv][col][0] = s[ni][r];
                    red[wv][col][1] = q[ni][r];
                }
        }
        __syncthreads();
        if (tid < 128) {
            int col = tid >> 1, st = tid & 1;
            float v = red[0][col][st] + red[1][col][st] + red[2][col][st] + red[3][col][st];
            part[((size_t)blockIdx.x * C + ncol0 + col) * 2 + st] = v;
        }
    }
}

extern "C" void kernel_launch(void* const* d_in, const int* in_sizes, int n_in,
                              void* d_out, int out_size, void* d_ws, size_t ws_size,
                              hipStream_t stream) {
    const float* f0    = (const float*)d_in[0];
    const float* f1    = (const float*)d_in[1];
    const float* f2    = (const float*)d_in[2];
    const float* f3    = (const float*)d_in[3];
    const float* bn_w2 = (const float*)d_in[4];
    const float* bn_b2 = (const float*)d_in[5];
    const float* W2    = (const float*)d_in[6];
    const float* bn_w1 = (const float*)d_in[7];
    const float* bn_b1 = (const float*)d_in[8];
    const float* W1    = (const float*)d_in[9];
    const float* bn_w0 = (const float*)d_in[10];
    const float* bn_b0 = (const float*)d_in[11];
    const float* W0    = (const float*)d_in[12];
    const int*   idx0  = (const int*)d_in[13];
    const int*   idx1  = (const int*)d_in[14];
    const int*   idx2  = (const int*)d_in[15];
    float* out = (float*)d_out;

    // ---- workspace layout ----
    unsigned short* f2p = (unsigned short*)d_ws;          // [PN2,256] bf16 (8MB)
    unsigned short* f1p = f2p + (size_t)PN2 * 256;        // [PN1,128] bf16 (16MB)
    int* cnt3 = (int*)(f1p + (size_t)PN1 * 128);          // zero region start
    int* cnt2 = cnt3 + PN3;
    int* cnt1 = cnt2 + PN2;                               // zero region end
    float* part2 = (float*)(cnt1 + PN1);                  // [256][512][2]
    float* part1 = part2 + 256 * 512 * 2;                 // [128][256][2]
    float* part0 = part1 + 128 * 256 * 2;                 // [256][128][2]
    float* scale2 = part0 + 256 * 128 * 2;
    float* shift2 = scale2 + 512;
    float* scale1 = shift2 + 512;
    float* shift1 = scale1 + 256;
    float* scale0 = shift1 + 256;
    float* shift0 = scale0 + 128;

    hipMemsetAsync(cnt3, 0, (size_t)(PN3 + PN2 + PN1) * sizeof(int), stream);

    hist_all<<<dim3(PN0 / 256, 3), 256, 0, stream>>>(idx0, idx1, idx2, cnt3, cnt2, cnt1);

    // ---- level 2: f2p = f2 + BN(f3[idx0]) @ W2' ----
    stats_f3<<<256, 256, 0, stream>>>(f3, cnt3, part2);
    redfin<<<512 / 32, 256, 0, stream>>>(part2, 256, 512, bn_w2, bn_b2, 1.f / PN2, scale2, shift2);
    gemm_stream<512, false, false, true, false>
        <<<dim3(128, 4), 256, 0, stream>>>(f3, idx0, W2, scale2, shift2, f2, f2p,
                                           cnt2, part1, PN2 / 16, 256);

    // ---- level 1: f1p = f1 + BN(f2p[idx1]) @ W1' ----
    redfin<<<256 / 32, 256, 0, stream>>>(part1, 128, 256, bn_w1, bn_b1, 1.f / PN1, scale1, shift1);
    gemm_stream<256, true, false, true, false>
        <<<dim3(256, 2), 256, 0, stream>>>(f2p, idx1, W1, scale1, shift1, f1, f1p,
                                           cnt1, part0, PN1 / 16, 128);

    // ---- level 0: out = f0 + BN(f1p[idx2]) @ W0' ----
    redfin<<<128 / 32, 256, 0, stream>>>(part0, 256, 128, bn_w0, bn_b0, 1.f / PN0, scale0, shift0);
    gemm_stream<128, true, true, false, true>
        <<<dim3(1024, 1), 256, 0, stream>>>(f1p, idx2, W0, scale0, shift0, f0, out,
                                            nullptr, nullptr, PN0 / 16, 64);
}